// Round 15
// baseline (213.875 us; speedup 1.0000x reference)
//
#include <hip/hip_runtime.h>

#define NNODES 149120
#define NEDGES 2385920
#define NB 64
#define NPMTS 2330
#define HEADK (NPMTS * 3)   // 6990
#define BN_EPS 1e-5f

#define NBUCK 512
#define BUCKET_N 292                    // 512*292 = 149504 >= NNODES
#define NCHUNK 1024
#define CHUNK_E (NEDGES / NCHUNK)       // 2330 (exact, even)
#define FPACK_SHIFT 9
#define FPACK_MASK 511u
#define CAP 5120                        // max edges per bucket (mean 4660, +6.7 sigma)

#define HEAD_SEG 32
#define SEGK ((HEADK + HEAD_SEG - 1) / HEAD_SEG)   // 219
#define BGRP 16                         // batch groups (512 head blocks)
#define BPB (NB / BGRP)                 // 4 batches per block

typedef _Float16 h16;
struct alignas(16) h8 { h16 v[8]; };
struct alignas(8)  h4 { h16 v[4]; };

// NT-load two consecutive ints as one 64-bit integer (builtin accepts scalar int types)
__device__ inline void nt_load2(const int* p, int& a, int& b) {
    long long v = __builtin_nontemporal_load((const long long*)p);
    a = (int)(unsigned)(v & 0xffffffffll);
    b = (int)(unsigned)((unsigned long long)v >> 32);
}

// ================= CSR build: count -> fused 2-level scan -> LDS-sorted bin -> per-bucket build =================

__global__ void k_count(const int* __restrict__ dst, int* __restrict__ counts,
                        int* __restrict__ done) {
    if (blockIdx.x == 0 && threadIdx.x < 2) done[threadIdx.x] = 0;   // reset completion counters
    __shared__ int c[NBUCK];
    c[threadIdx.x] = 0; c[threadIdx.x + 256] = 0;
    __syncthreads();
    const int* base = dst + blockIdx.x * CHUNK_E;
    for (int i = threadIdx.x; i < CHUNK_E / 2; i += 256) {
        int d0, d1;
        nt_load2(base + 2 * i, d0, d1);
        atomicAdd(&c[d0 / BUCKET_N], 1);
        atomicAdd(&c[d1 / BUCKET_N], 1);
    }
    __syncthreads();
    counts[threadIdx.x * NCHUNK + blockIdx.x] = c[threadIdx.x];
    counts[(threadIdx.x + 256) * NCHUNK + blockIdx.x] = c[threadIdx.x + 256];
}

// fused scan: per-bucket scan over 1024 chunk counts; last-arriving block scans the 512 bucket totals
__global__ __launch_bounds__(256) void k_scanAB(const int* __restrict__ counts,
                                                int* __restrict__ bases,
                                                int* __restrict__ btot,
                                                int* __restrict__ bstart,
                                                int* __restrict__ done) {
    __shared__ int s[256];
    __shared__ bool amLast;
    int b = blockIdx.x, t = threadIdx.x;
    const int4* row = (const int4*)(counts + b * NCHUNK);
    int4 v = row[t];
    int sum = v.x + v.y + v.z + v.w;
    s[t] = sum;
    __syncthreads();
    for (int o = 1; o < 256; o <<= 1) {
        int x = (t >= o) ? s[t - o] : 0;
        __syncthreads();
        s[t] += x;
        __syncthreads();
    }
    int run = t ? s[t - 1] : 0;
    int4 o;
    o.x = run;
    o.y = run + v.x;
    o.z = run + v.x + v.y;
    o.w = run + v.x + v.y + v.z;
    ((int4*)(bases + b * NCHUNK))[t] = o;
    if (t == 255) btot[b] = s[255];
    // completion: canonical threadfence-reduction pattern
    __syncthreads();
    __threadfence();
    if (t == 0) {
        unsigned prev = atomicAdd((unsigned*)done, 1u);
        amLast = (prev == (unsigned)gridDim.x - 1u);
    }
    __syncthreads();
    if (!amLast) return;
    // last block: pair-scan 512 bucket totals -> bstart[513]
    int v0 = btot[2 * t], v1 = btot[2 * t + 1];
    s[t] = v0 + v1;
    __syncthreads();
    for (int o2 = 1; o2 < 256; o2 <<= 1) {
        int x = (t >= o2) ? s[t - o2] : 0;
        __syncthreads();
        s[t] += x;
        __syncthreads();
    }
    int excl = t ? s[t - 1] : 0;
    bstart[2 * t] = excl;
    bstart[2 * t + 1] = excl + v0;
    if (t == 255) bstart[NBUCK] = s[255];
}

// per-chunk LDS counting sort by bucket, then 4-lane-group bucket-run coalesced write-out
__global__ __launch_bounds__(256) void k_bin_sorted(const int* __restrict__ src,
                                                    const int* __restrict__ dst,
                                                    const int* __restrict__ bases,
                                                    const int* __restrict__ bstart,
                                                    unsigned* __restrict__ packed) {
    __shared__ unsigned ds[CHUNK_E];     // 9.3 KB
    __shared__ unsigned outp[CHUNK_E];   // 9.3 KB
    __shared__ int hist[NBUCK];          // doubles as cursor
    __shared__ int basel[NBUCK + 1];
    __shared__ int gbase[NBUCK];
    __shared__ int s[256];
    int t = threadIdx.x;
    int e0 = blockIdx.x * CHUNK_E;
    hist[t] = 0; hist[t + 256] = 0;
    gbase[t] = bstart[t] + bases[t * NCHUNK + blockIdx.x];
    gbase[t + 256] = bstart[t + 256] + bases[(t + 256) * NCHUNK + blockIdx.x];
    __syncthreads();
    // pass 1: stage dst in LDS (64b NT stream) + bucket histogram
    for (int i = t; i < CHUNK_E / 2; i += 256) {
        int d0, d1;
        nt_load2(dst + e0 + 2 * i, d0, d1);
        ds[2 * i] = (unsigned)d0;
        ds[2 * i + 1] = (unsigned)d1;
        atomicAdd(&hist[d0 / BUCKET_N], 1);
        atomicAdd(&hist[d1 / BUCKET_N], 1);
    }
    __syncthreads();
    // pair scan: thread t owns entries 2t, 2t+1 (hv0/hv1 captured in regs before overwrite)
    int hv0 = hist[2 * t], hv1 = hist[2 * t + 1];
    s[t] = hv0 + hv1;
    __syncthreads();
    for (int o = 1; o < 256; o <<= 1) {
        int x = (t >= o) ? s[t - o] : 0;
        __syncthreads();
        s[t] += x;
        __syncthreads();
    }
    int excl = t ? s[t - 1] : 0;
    basel[2 * t] = excl;
    basel[2 * t + 1] = excl + hv0;
    if (t == 255) basel[NBUCK] = s[255];
    hist[2 * t] = excl;           // cursor
    hist[2 * t + 1] = excl + hv0;
    __syncthreads();
    // pass 2: scatter into LDS (dst from LDS, src streamed 64b NT)
    for (int i = t; i < CHUNK_E / 2; i += 256) {
        int sv0, sv1;
        nt_load2(src + e0 + 2 * i, sv0, sv1);
        unsigned d0 = ds[2 * i], d1 = ds[2 * i + 1];
        unsigned b0 = d0 / BUCKET_N;
        int p0 = atomicAdd(&hist[b0], 1);
        outp[p0] = ((unsigned)sv0 << FPACK_SHIFT) | (d0 - b0 * BUCKET_N);
        unsigned b1 = d1 / BUCKET_N;
        int p1 = atomicAdd(&hist[b1], 1);
        outp[p1] = ((unsigned)sv1 << FPACK_SHIFT) | (d1 - b1 * BUCKET_N);
    }
    __syncthreads();
    // write-out: 64 groups of 4 lanes; group handles buckets gid, gid+64, ... (runs ~4.5 words)
    int gid = t >> 2, glane = t & 3;
    for (int b = gid; b < NBUCK; b += 64) {
        int s0 = basel[b], s1 = basel[b + 1], gb = gbase[b];
        for (int i = s0 + glane; i < s1; i += 4)
            packed[gb + (i - s0)] = outp[i];
    }
}

// one block per bucket: deg hist -> scan -> csr scatter (LDS) + coalesced writes; also xs8h = x*dinv (fp16)
__global__ __launch_bounds__(256) void k_build(const unsigned* __restrict__ packed,
                                               const int* __restrict__ bstart,
                                               const float* __restrict__ x,
                                               int* __restrict__ deg, int* __restrict__ rowstart,
                                               float* __restrict__ dinv, int* __restrict__ csr,
                                               h8* __restrict__ xs8h) {
    __shared__ int csr_l[CAP];     // 20 KB
    __shared__ int ldeg[NBUCK];    // 2 KB (>= BUCKET_N)
    __shared__ int lrow[NBUCK];
    __shared__ int part[256];
    int t = threadIdx.x;
    int b = blockIdx.x;
    int lo = bstart[b], hi = bstart[b + 1];
    int len = hi - lo;
    if (len > CAP) len = CAP;
    ldeg[2 * t] = 0; ldeg[2 * t + 1] = 0;
    __syncthreads();
    for (int i = t; i < len; i += 256)
        atomicAdd(&ldeg[packed[lo + i] & FPACK_MASK], 1);
    __syncthreads();
    int a0 = ldeg[2 * t], a1 = ldeg[2 * t + 1];
    part[t] = a0 + a1;
    __syncthreads();
    for (int o = 1; o < 256; o <<= 1) {
        int xg = (t >= o) ? part[t - o] : 0;
        __syncthreads();
        part[t] += xg;
        __syncthreads();
    }
    int run = t ? part[t - 1] : 0;
    lrow[2 * t] = run;
    lrow[2 * t + 1] = run + a0;
    __syncthreads();
    int n0 = b * BUCKET_N;
    int nnode = NNODES - n0; if (nnode > BUCKET_N) nnode = BUCKET_N;
    if (nnode < 0) nnode = 0;
    for (int l = t; l < nnode; l += 256) {
        int dg = ldeg[l];
        int n = n0 + l;
        float di = rsqrtf((float)(dg + 1));
        deg[n] = dg;
        rowstart[n] = lo + lrow[l];
        dinv[n] = di;
        h8 o;
#pragma unroll
        for (int c = 0; c < 5; ++c) o.v[c] = (h16)(x[(unsigned)n * 5u + c] * di);
        o.v[5] = (h16)0.f; o.v[6] = (h16)0.f; o.v[7] = (h16)0.f;
        xs8h[n] = o;
    }
    __syncthreads();   // node loop reads ldeg[l] (l ≡ t mod 256); cursor writes ldeg[2t,2t+1]
    ldeg[2 * t] = lrow[2 * t];            // cursor
    ldeg[2 * t + 1] = lrow[2 * t + 1];
    __syncthreads();
    for (int i = t; i < len; i += 256) {
        unsigned v = packed[lo + i];
        int pos = atomicAdd(&ldeg[v & FPACK_MASK], 1);
        csr_l[pos] = (int)(v >> FPACK_SHIFT);
    }
    __syncthreads();
    for (int i = t; i < len; i += 256) csr[lo + i] = csr_l[i];
}

// ================= GCN layers (fp16 gather operands, fp32 math) =================

// layer1 gather (node per lane) + fused mm1 + relu + mm2 + prescale -> g2sh (16 x fp16)
__global__ __launch_bounds__(256) void g8h_mm12(const int* __restrict__ rowstart,
                                                const int* __restrict__ deg,
                                                const int* __restrict__ csr,
                                                const h8* __restrict__ xs8h,
                                                const float* __restrict__ dinv,
                                                const float* __restrict__ W1,
                                                const float* __restrict__ b1,
                                                const float* __restrict__ W2,
                                                h8* __restrict__ g2sh) {
    __shared__ float W1s[5 * 32], W2s[32 * 16], b1s[32];
    int tid = threadIdx.x;
    if (tid < 5 * 32) W1s[tid] = W1[tid];
    if (tid < 32) b1s[tid] = b1[tid];
    for (int i = tid; i < 32 * 16; i += 256) W2s[i] = W2[i];
    __syncthreads();

    unsigned n = blockIdx.x * 256u + tid;
    if (n >= NNODES) return;
    int rs = rowstart[n], d = deg[n];
    float acc[8];
    {
        h8 s = xs8h[n];
#pragma unroll
        for (int k = 0; k < 8; ++k) acc[k] = (float)s.v[k];
    }
    int j = 0;
    for (; j + 4 <= d; j += 4) {
        int s0 = csr[rs + j], s1 = csr[rs + j + 1], s2 = csr[rs + j + 2], s3 = csr[rs + j + 3];
        h8 a = xs8h[s0], bb = xs8h[s1], cc = xs8h[s2], dd = xs8h[s3];
#pragma unroll
        for (int k = 0; k < 8; ++k)
            acc[k] += ((float)a.v[k] + (float)bb.v[k]) + ((float)cc.v[k] + (float)dd.v[k]);
    }
    for (; j < d; ++j) {
        h8 a = xs8h[csr[rs + j]];
#pragma unroll
        for (int k = 0; k < 8; ++k) acc[k] += (float)a.v[k];
    }
    float di = dinv[n];
    float a5[5];
#pragma unroll
    for (int k = 0; k < 5; ++k) a5[k] = acc[k] * di;
    float g[16];
#pragma unroll
    for (int c = 0; c < 16; ++c) g[c] = 0.f;
#pragma unroll
    for (int jj = 0; jj < 32; ++jj) {
        float hv = b1s[jj];
#pragma unroll
        for (int k = 0; k < 5; ++k) hv += a5[k] * W1s[k * 32 + jj];
        hv = hv > 0.f ? hv : 0.f;
#pragma unroll
        for (int c = 0; c < 16; ++c) g[c] += hv * W2s[jj * 16 + c];
    }
    h8 o0, o1;
#pragma unroll
    for (int c = 0; c < 8; ++c) {
        o0.v[c] = (h16)(g[c] * di);
        o1.v[c] = (h16)(g[c + 8] * di);
    }
    g2sh[n * 2u] = o0;
    g2sh[n * 2u + 1] = o1;
}

// layer2 gather (2 lanes per node, 8ch each) + relu + mm3 + prescale -> g3s4h (4 x fp16)
__global__ __launch_bounds__(256) void g16h_mm3(const int* __restrict__ rowstart,
                                                const int* __restrict__ deg,
                                                const int* __restrict__ csr,
                                                const h8* __restrict__ g2sh,
                                                const float* __restrict__ dinv,
                                                const float* __restrict__ b2,
                                                const float* __restrict__ W3,
                                                h4* __restrict__ g3s4h) {
    __shared__ float W3s[16 * 3], b2s[16];
    int tid = threadIdx.x;
    if (tid < 16 * 3) W3s[tid] = W3[tid];
    if (tid < 16) b2s[tid] = b2[tid];
    __syncthreads();
    unsigned t = blockIdx.x * 256u + tid;
    unsigned g = t >> 1, c = t & 1u;
    if (g >= NNODES) return;
    int rs = rowstart[g], d = deg[g];
    float acc[8];
    {
        h8 s = g2sh[g * 2u + c];
#pragma unroll
        for (int k = 0; k < 8; ++k) acc[k] = (float)s.v[k];
    }
    int j = 0;
    for (; j + 4 <= d; j += 4) {
        int s0 = csr[rs + j], s1 = csr[rs + j + 1], s2 = csr[rs + j + 2], s3 = csr[rs + j + 3];
        h8 a = g2sh[(unsigned)s0 * 2u + c], bb = g2sh[(unsigned)s1 * 2u + c];
        h8 cc = g2sh[(unsigned)s2 * 2u + c], dd = g2sh[(unsigned)s3 * 2u + c];
#pragma unroll
        for (int k = 0; k < 8; ++k)
            acc[k] += ((float)a.v[k] + (float)bb.v[k]) + ((float)cc.v[k] + (float)dd.v[k]);
    }
    for (; j < d; ++j) {
        h8 a = g2sh[(unsigned)csr[rs + j] * 2u + c];
#pragma unroll
        for (int k = 0; k < 8; ++k) acc[k] += (float)a.v[k];
    }
    float di = dinv[g];
    float p0 = 0.f, p1 = 0.f, p2 = 0.f;
#pragma unroll
    for (int jj = 0; jj < 8; ++jj) {
        int ch = c * 8 + jj;
        float v = acc[jj] * di + b2s[ch];
        v = v > 0.f ? v : 0.f;
        p0 += v * W3s[ch * 3 + 0];
        p1 += v * W3s[ch * 3 + 1];
        p2 += v * W3s[ch * 3 + 2];
    }
    p0 += __shfl_xor(p0, 1);
    p1 += __shfl_xor(p1, 1);
    p2 += __shfl_xor(p2, 1);
    if (c == 0) {
        h4 o;
        o.v[0] = (h16)(p0 * di);
        o.v[1] = (h16)(p1 * di);
        o.v[2] = (h16)(p2 * di);
        o.v[3] = (h16)0.f;
        g3s4h[g] = o;
    }
}

// layer3 gather (node per lane) + bias + relu -> h3 fp32
__global__ __launch_bounds__(256) void g4h_final(const int* __restrict__ rowstart,
                                                 const int* __restrict__ deg,
                                                 const int* __restrict__ csr,
                                                 const h4* __restrict__ g3,
                                                 const float* __restrict__ dinv,
                                                 const float* __restrict__ b3,
                                                 float* __restrict__ h3) {
    unsigned g = blockIdx.x * 256u + threadIdx.x;
    if (g >= NNODES) return;
    int rs = rowstart[g], d = deg[g];
    float a0, a1, a2;
    {
        h4 s = g3[g];
        a0 = (float)s.v[0]; a1 = (float)s.v[1]; a2 = (float)s.v[2];
    }
    int j = 0;
    for (; j + 2 <= d; j += 2) {
        h4 v0 = g3[csr[rs + j]], v1 = g3[csr[rs + j + 1]];
        a0 += (float)v0.v[0] + (float)v1.v[0];
        a1 += (float)v0.v[1] + (float)v1.v[1];
        a2 += (float)v0.v[2] + (float)v1.v[2];
    }
    for (; j < d; ++j) {
        h4 v = g3[csr[rs + j]];
        a0 += (float)v.v[0]; a1 += (float)v.v[1]; a2 += (float)v.v[2];
    }
    float di = dinv[g];
    float o0 = a0 * di + b3[0];
    float o1 = a1 * di + b3[1];
    float o2 = a2 * di + b3[2];
    h3[g * 3u + 0] = o0 > 0.f ? o0 : 0.f;
    h3[g * 3u + 1] = o1 > 0.f ? o1 : 0.f;
    h3[g * 3u + 2] = o2 > 0.f ? o2 : 0.f;
}

// ================= head + fused BN/final-linear (last-block) =================

__global__ __launch_bounds__(256) void k_headbn(const float* __restrict__ h3,
                                                const float* __restrict__ Wl1,
                                                float* __restrict__ zpart,
                                                const float* __restrict__ bl1,
                                                const float* __restrict__ gamma,
                                                const float* __restrict__ beta,
                                                const float* __restrict__ Wl2,
                                                const float* __restrict__ bl2,
                                                float* __restrict__ out,
                                                int* __restrict__ done) {
    __shared__ float Wl1s[SEGK * 32];   // 28 KB
    __shared__ float hrow[SEGK];
    __shared__ float part[8][32];
    __shared__ bool amLast;
    int seg = blockIdx.x & 31, bg = blockIdx.x >> 5;
    int tid = threadIdx.x;
    int k0 = seg * SEGK;
    int cnt = HEADK - k0; if (cnt > SEGK) cnt = SEGK;
    for (int i = tid; i < cnt * 32; i += 256) Wl1s[i] = Wl1[k0 * 32 + i];
    int j = tid & 31, kg = tid >> 5;
    for (int bb = 0; bb < BPB; ++bb) {
        int b = bg * BPB + bb;
        __syncthreads();
        for (int k = tid; k < cnt; k += 256) hrow[k] = h3[b * HEADK + k0 + k];
        __syncthreads();
        float acc = 0.f;
        for (int k = kg; k < cnt; k += 8) acc += hrow[k] * Wl1s[k * 32 + j];
        part[kg][j] = acc;
        __syncthreads();
        if (tid < 32) {
            float s = 0.f;
#pragma unroll
            for (int g2 = 0; g2 < 8; ++g2) s += part[g2][tid];
            zpart[(seg * NB + b) * 32 + tid] = s;
        }
    }
    // completion: canonical threadfence-reduction pattern
    __syncthreads();
    __threadfence();
    if (tid == 0) {
        unsigned prev = atomicAdd((unsigned*)done, 1u);
        amLast = (prev == (unsigned)gridDim.x - 1u);
    }
    __syncthreads();
    if (!amLast) return;

    // ---- BN (biased var) + ReLU + final linear, executed by the last block
    __shared__ float zs[NB][32];
    __shared__ float scale[32], shift[32];
    for (int i = tid; i < NB * 32; i += 256) {
        float v = bl1[i & 31];
#pragma unroll
        for (int sgm = 0; sgm < HEAD_SEG; ++sgm) v += zpart[sgm * NB * 32 + i];
        zs[i >> 5][i & 31] = v;
    }
    __syncthreads();
    if (tid < 32) {
        float m = 0.f, v = 0.f;
        for (int b = 0; b < NB; ++b) { float xv = zs[b][tid]; m += xv; v += xv * xv; }
        m /= (float)NB;
        v = v / (float)NB - m * m;
        float sc = gamma[tid] * rsqrtf(v + BN_EPS);
        scale[tid] = sc;
        shift[tid] = beta[tid] - m * sc;
    }
    __syncthreads();
    if (tid < NB) {
        float acc = bl2[0];
#pragma unroll
        for (int jj = 0; jj < 32; ++jj) {
            float zv = zs[tid][jj] * scale[jj] + shift[jj];
            zv = zv > 0.f ? zv : 0.f;
            acc += zv * Wl2[jj];
        }
        out[tid] = acc;
    }
}

// ================= launch =================

extern "C" void kernel_launch(void* const* d_in, const int* in_sizes, int n_in,
                              void* d_out, int out_size, void* d_ws, size_t ws_size,
                              hipStream_t stream) {
    const float* x    = (const float*)d_in[0];
    const int*   ei   = (const int*)d_in[1];
    const float* W1   = (const float*)d_in[2];
    const float* b1   = (const float*)d_in[3];
    const float* W2   = (const float*)d_in[4];
    const float* b2   = (const float*)d_in[5];
    const float* W3   = (const float*)d_in[6];
    const float* b3   = (const float*)d_in[7];
    const float* Wl1  = (const float*)d_in[8];
    const float* bl1  = (const float*)d_in[9];
    const float* gamma= (const float*)d_in[10];
    const float* beta = (const float*)d_in[11];
    const float* Wl2  = (const float*)d_in[12];
    const float* bl2  = (const float*)d_in[13];

    const int* src = ei;            // edge_index[0]
    const int* dst = ei + NEDGES;   // edge_index[1]

    char* ws = (char*)d_ws;
    size_t off = 0;
    float*    dinv     = (float*)   (ws + off); off += (size_t)NNODES * 4;
    int*      deg      = (int*)     (ws + off); off += (size_t)NNODES * 4;
    int*      counts   = (int*)     (ws + off); off += (size_t)NBUCK * NCHUNK * 4;
    int*      bases    = (int*)     (ws + off); off += (size_t)NBUCK * NCHUNK * 4;
    int*      btot     = (int*)     (ws + off); off += (size_t)NBUCK * 4;
    int*      bstart   = (int*)     (ws + off); off += (size_t)(NBUCK + 1) * 4;
    int*      done     = (int*)     (ws + off); off += (size_t)2 * 4;
    off = (off + 255) & ~(size_t)255;
    unsigned* packed   = (unsigned*)(ws + off); off += (size_t)NEDGES * 4;
    int*      rowstart = (int*)     (ws + off); off += (size_t)NNODES * 4;
    int*      csr      = (int*)     (ws + off); off += (size_t)NEDGES * 4;
    h8*       xs8h     = (h8*)      (ws + off); off += (size_t)NNODES * 16;
    h8*       g2sh     = (h8*)      (ws + off); off += (size_t)NNODES * 32;
    h4*       g3s4h    = (h4*)      (ws + off); off += (size_t)NNODES * 8;
    float*    h3       = (float*)   (ws + off); off += (size_t)NNODES * 3 * 4;
    float*    zpart    = (float*)   (ws + off); off += (size_t)HEAD_SEG * NB * 32 * 4;

    float* outp = (float*)d_out;

    // ---- CSR build (all global stores coalesced; scatter staged in LDS) + fused x*dinv fp16 pack
    k_count<<<NCHUNK, 256, 0, stream>>>(dst, counts, done);
    k_scanAB<<<NBUCK, 256, 0, stream>>>(counts, bases, btot, bstart, done + 0);
    k_bin_sorted<<<NCHUNK, 256, 0, stream>>>(src, dst, bases, bstart, packed);
    k_build<<<NBUCK, 256, 0, stream>>>(packed, bstart, x, deg, rowstart, dinv, csr, xs8h);

    // ---- layer1 gather + mm1 + relu + mm2 + prescale
    g8h_mm12<<<(NNODES + 255) / 256, 256, 0, stream>>>(
        rowstart, deg, csr, xs8h, dinv, W1, b1, W2, g2sh);

    // ---- layer2 gather + relu + mm3 + prescale
    g16h_mm3<<<(int)(((unsigned)NNODES * 2u + 255) / 256), 256, 0, stream>>>(
        rowstart, deg, csr, g2sh, dinv, b2, W3, g3s4h);

    // ---- layer3 gather + bias + relu
    g4h_final<<<(NNODES + 255) / 256, 256, 0, stream>>>(
        rowstart, deg, csr, g3s4h, dinv, b3, h3);

    // ---- head + fused BN + final linear (last-block epilogue)
    k_headbn<<<HEAD_SEG * BGRP, 256, 0, stream>>>(
        h3, Wl1, zpart, bl1, gamma, beta, Wl2, bl2, outp, done + 1);
}

// Round 16
// 149.231 us; speedup vs baseline: 1.4332x; 1.4332x over previous
//
#include <hip/hip_runtime.h>

#define NNODES 149120
#define NEDGES 2385920
#define NB 64
#define NPMTS 2330
#define HEADK (NPMTS * 3)   // 6990
#define BN_EPS 1e-5f

#define NBUCK 512
#define BUCKET_N 292                    // 512*292 = 149504 >= NNODES
#define NCHUNK 1024
#define CHUNK_E (NEDGES / NCHUNK)       // 2330 (exact, even)
#define FPACK_SHIFT 9
#define FPACK_MASK 511u
#define CAP 5120                        // max edges per bucket (mean 4672, sigma ~68)

#define HEAD_SEG 32
#define SEGK ((HEADK + HEAD_SEG - 1) / HEAD_SEG)   // 219
#define BGRP 16                         // batch groups (512 head blocks)
#define BPB (NB / BGRP)                 // 4 batches per block

typedef _Float16 h16;
struct alignas(16) h8 { h16 v[8]; };
struct alignas(8)  h4 { h16 v[4]; };

// NT-load two consecutive ints as one 64-bit integer (builtin accepts scalar int types)
__device__ inline void nt_load2(const int* p, int& a, int& b) {
    long long v = __builtin_nontemporal_load((const long long*)p);
    a = (int)(unsigned)(v & 0xffffffffll);
    b = (int)(unsigned)((unsigned long long)v >> 32);
}

// ================= CSR build: count -> 2-level scan -> LDS-sorted bin -> per-bucket build =================

__global__ void k_count(const int* __restrict__ dst, int* __restrict__ counts) {
    __shared__ int c[NBUCK];
    c[threadIdx.x] = 0; c[threadIdx.x + 256] = 0;
    __syncthreads();
    const int* base = dst + blockIdx.x * CHUNK_E;
    for (int i = threadIdx.x; i < CHUNK_E / 2; i += 256) {
        int d0, d1;
        nt_load2(base + 2 * i, d0, d1);
        atomicAdd(&c[d0 / BUCKET_N], 1);
        atomicAdd(&c[d1 / BUCKET_N], 1);
    }
    __syncthreads();
    counts[threadIdx.x * NCHUNK + blockIdx.x] = c[threadIdx.x];
    counts[(threadIdx.x + 256) * NCHUNK + blockIdx.x] = c[threadIdx.x + 256];
}

// level A: per-bucket exclusive scan over its 1024 chunk counts (coalesced int4), emit bucket total
__global__ void k_scanA(const int* __restrict__ counts, int* __restrict__ bases,
                        int* __restrict__ btot) {
    __shared__ int s[256];
    int b = blockIdx.x, t = threadIdx.x;
    const int4* row = (const int4*)(counts + b * NCHUNK);
    int4 v = row[t];
    int sum = v.x + v.y + v.z + v.w;
    s[t] = sum;
    __syncthreads();
    for (int o = 1; o < 256; o <<= 1) {
        int x = (t >= o) ? s[t - o] : 0;
        __syncthreads();
        s[t] += x;
        __syncthreads();
    }
    int run = t ? s[t - 1] : 0;
    int4 o;
    o.x = run;
    o.y = run + v.x;
    o.z = run + v.x + v.y;
    o.w = run + v.x + v.y + v.z;
    ((int4*)(bases + b * NCHUNK))[t] = o;
    if (t == 255) btot[b] = s[255];
}

// level B: exclusive scan of 512 bucket totals -> bstart[513]
__global__ void k_scanB(const int* __restrict__ btot, int* __restrict__ bstart) {
    __shared__ int s[NBUCK];
    int t = threadIdx.x;   // 512
    int v = btot[t];
    s[t] = v;
    __syncthreads();
    for (int o = 1; o < NBUCK; o <<= 1) {
        int x = (t >= o) ? s[t - o] : 0;
        __syncthreads();
        s[t] += x;
        __syncthreads();
    }
    bstart[t] = s[t] - v;
    if (t == NBUCK - 1) bstart[NBUCK] = s[NBUCK - 1];
}

// per-chunk LDS counting sort by bucket, then 4-lane-group bucket-run coalesced write-out
__global__ __launch_bounds__(256) void k_bin_sorted(const int* __restrict__ src,
                                                    const int* __restrict__ dst,
                                                    const int* __restrict__ bases,
                                                    const int* __restrict__ bstart,
                                                    unsigned* __restrict__ packed) {
    __shared__ unsigned ds[CHUNK_E];     // 9.3 KB
    __shared__ unsigned outp[CHUNK_E];   // 9.3 KB
    __shared__ int hist[NBUCK];          // doubles as cursor
    __shared__ int basel[NBUCK + 1];
    __shared__ int gbase[NBUCK];
    __shared__ int s[256];
    int t = threadIdx.x;
    int e0 = blockIdx.x * CHUNK_E;
    hist[t] = 0; hist[t + 256] = 0;
    gbase[t] = bstart[t] + bases[t * NCHUNK + blockIdx.x];
    gbase[t + 256] = bstart[t + 256] + bases[(t + 256) * NCHUNK + blockIdx.x];
    __syncthreads();
    // pass 1: stage dst in LDS (64b NT stream) + bucket histogram
    for (int i = t; i < CHUNK_E / 2; i += 256) {
        int d0, d1;
        nt_load2(dst + e0 + 2 * i, d0, d1);
        ds[2 * i] = (unsigned)d0;
        ds[2 * i + 1] = (unsigned)d1;
        atomicAdd(&hist[d0 / BUCKET_N], 1);
        atomicAdd(&hist[d1 / BUCKET_N], 1);
    }
    __syncthreads();
    // pair scan: thread t owns entries 2t, 2t+1 (hv0/hv1 captured in regs before overwrite)
    int hv0 = hist[2 * t], hv1 = hist[2 * t + 1];
    s[t] = hv0 + hv1;
    __syncthreads();
    for (int o = 1; o < 256; o <<= 1) {
        int x = (t >= o) ? s[t - o] : 0;
        __syncthreads();
        s[t] += x;
        __syncthreads();
    }
    int excl = t ? s[t - 1] : 0;
    basel[2 * t] = excl;
    basel[2 * t + 1] = excl + hv0;
    if (t == 255) basel[NBUCK] = s[255];
    hist[2 * t] = excl;           // cursor
    hist[2 * t + 1] = excl + hv0;
    __syncthreads();
    // pass 2: scatter into LDS (dst from LDS, src streamed 64b NT)
    for (int i = t; i < CHUNK_E / 2; i += 256) {
        int sv0, sv1;
        nt_load2(src + e0 + 2 * i, sv0, sv1);
        unsigned d0 = ds[2 * i], d1 = ds[2 * i + 1];
        unsigned b0 = d0 / BUCKET_N;
        int p0 = atomicAdd(&hist[b0], 1);
        outp[p0] = ((unsigned)sv0 << FPACK_SHIFT) | (d0 - b0 * BUCKET_N);
        unsigned b1 = d1 / BUCKET_N;
        int p1 = atomicAdd(&hist[b1], 1);
        outp[p1] = ((unsigned)sv1 << FPACK_SHIFT) | (d1 - b1 * BUCKET_N);
    }
    __syncthreads();
    // write-out: 64 groups of 4 lanes; group handles buckets gid, gid+64, ... (runs ~4.5 words)
    int gid = t >> 2, glane = t & 3;
    for (int b = gid; b < NBUCK; b += 64) {
        int s0 = basel[b], s1 = basel[b + 1], gb = gbase[b];
        for (int i = s0 + glane; i < s1; i += 4)
            packed[gb + (i - s0)] = outp[i];
    }
}

// one block per bucket: deg hist -> scan -> csr scatter (LDS) + coalesced writes; also xs8h = x*dinv (fp16)
__global__ __launch_bounds__(256) void k_build(const unsigned* __restrict__ packed,
                                               const int* __restrict__ bstart,
                                               const float* __restrict__ x,
                                               int* __restrict__ deg, int* __restrict__ rowstart,
                                               float* __restrict__ dinv, int* __restrict__ csr,
                                               h8* __restrict__ xs8h) {
    __shared__ int csr_l[CAP];     // 20 KB
    __shared__ int ldeg[NBUCK];    // 2 KB (>= BUCKET_N)
    __shared__ int lrow[NBUCK];
    __shared__ int part[256];
    int t = threadIdx.x;
    int b = blockIdx.x;
    int lo = bstart[b], hi = bstart[b + 1];
    int len = hi - lo;
    if (len > CAP) len = CAP;
    ldeg[2 * t] = 0; ldeg[2 * t + 1] = 0;
    __syncthreads();
    for (int i = t; i < len; i += 256)
        atomicAdd(&ldeg[packed[lo + i] & FPACK_MASK], 1);
    __syncthreads();
    int a0 = ldeg[2 * t], a1 = ldeg[2 * t + 1];
    part[t] = a0 + a1;
    __syncthreads();
    for (int o = 1; o < 256; o <<= 1) {
        int xg = (t >= o) ? part[t - o] : 0;
        __syncthreads();
        part[t] += xg;
        __syncthreads();
    }
    int run = t ? part[t - 1] : 0;
    lrow[2 * t] = run;
    lrow[2 * t + 1] = run + a0;
    __syncthreads();
    int n0 = b * BUCKET_N;
    int nnode = NNODES - n0; if (nnode > BUCKET_N) nnode = BUCKET_N;
    if (nnode < 0) nnode = 0;
    for (int l = t; l < nnode; l += 256) {
        int dg = ldeg[l];
        int n = n0 + l;
        float di = rsqrtf((float)(dg + 1));
        deg[n] = dg;
        rowstart[n] = lo + lrow[l];
        dinv[n] = di;
        h8 o;
#pragma unroll
        for (int c = 0; c < 5; ++c) o.v[c] = (h16)(x[(unsigned)n * 5u + c] * di);
        o.v[5] = (h16)0.f; o.v[6] = (h16)0.f; o.v[7] = (h16)0.f;
        xs8h[n] = o;
    }
    __syncthreads();   // node loop reads ldeg[l] (l ≡ t mod 256); cursor writes ldeg[2t,2t+1]
    ldeg[2 * t] = lrow[2 * t];            // cursor
    ldeg[2 * t + 1] = lrow[2 * t + 1];
    __syncthreads();
    for (int i = t; i < len; i += 256) {
        unsigned v = packed[lo + i];
        int pos = atomicAdd(&ldeg[v & FPACK_MASK], 1);
        csr_l[pos] = (int)(v >> FPACK_SHIFT);
    }
    __syncthreads();
    for (int i = t; i < len; i += 256) csr[lo + i] = csr_l[i];
}

// ================= GCN layers (fp16 gather operands, fp32 math) =================

// layer1 gather (node per lane) + fused mm1 + relu + mm2 + prescale -> g2sh (16 x fp16)
__global__ __launch_bounds__(256) void g8h_mm12(const int* __restrict__ rowstart,
                                                const int* __restrict__ deg,
                                                const int* __restrict__ csr,
                                                const h8* __restrict__ xs8h,
                                                const float* __restrict__ dinv,
                                                const float* __restrict__ W1,
                                                const float* __restrict__ b1,
                                                const float* __restrict__ W2,
                                                h8* __restrict__ g2sh) {
    __shared__ float W1s[5 * 32], W2s[32 * 16], b1s[32];
    int tid = threadIdx.x;
    if (tid < 5 * 32) W1s[tid] = W1[tid];
    if (tid < 32) b1s[tid] = b1[tid];
    for (int i = tid; i < 32 * 16; i += 256) W2s[i] = W2[i];
    __syncthreads();

    unsigned n = blockIdx.x * 256u + tid;
    if (n >= NNODES) return;
    int rs = rowstart[n], d = deg[n];
    float acc[8];
    {
        h8 s = xs8h[n];
#pragma unroll
        for (int k = 0; k < 8; ++k) acc[k] = (float)s.v[k];
    }
    int j = 0;
    for (; j + 4 <= d; j += 4) {
        int s0 = csr[rs + j], s1 = csr[rs + j + 1], s2 = csr[rs + j + 2], s3 = csr[rs + j + 3];
        h8 a = xs8h[s0], bb = xs8h[s1], cc = xs8h[s2], dd = xs8h[s3];
#pragma unroll
        for (int k = 0; k < 8; ++k)
            acc[k] += ((float)a.v[k] + (float)bb.v[k]) + ((float)cc.v[k] + (float)dd.v[k]);
    }
    for (; j < d; ++j) {
        h8 a = xs8h[csr[rs + j]];
#pragma unroll
        for (int k = 0; k < 8; ++k) acc[k] += (float)a.v[k];
    }
    float di = dinv[n];
    float a5[5];
#pragma unroll
    for (int k = 0; k < 5; ++k) a5[k] = acc[k] * di;
    float g[16];
#pragma unroll
    for (int c = 0; c < 16; ++c) g[c] = 0.f;
#pragma unroll
    for (int jj = 0; jj < 32; ++jj) {
        float hv = b1s[jj];
#pragma unroll
        for (int k = 0; k < 5; ++k) hv += a5[k] * W1s[k * 32 + jj];
        hv = hv > 0.f ? hv : 0.f;
#pragma unroll
        for (int c = 0; c < 16; ++c) g[c] += hv * W2s[jj * 16 + c];
    }
    h8 o0, o1;
#pragma unroll
    for (int c = 0; c < 8; ++c) {
        o0.v[c] = (h16)(g[c] * di);
        o1.v[c] = (h16)(g[c + 8] * di);
    }
    g2sh[n * 2u] = o0;
    g2sh[n * 2u + 1] = o1;
}

// layer2 gather (2 lanes per node, 8ch each) + relu + mm3 + prescale -> g3s4h (4 x fp16)
__global__ __launch_bounds__(256) void g16h_mm3(const int* __restrict__ rowstart,
                                                const int* __restrict__ deg,
                                                const int* __restrict__ csr,
                                                const h8* __restrict__ g2sh,
                                                const float* __restrict__ dinv,
                                                const float* __restrict__ b2,
                                                const float* __restrict__ W3,
                                                h4* __restrict__ g3s4h) {
    __shared__ float W3s[16 * 3], b2s[16];
    int tid = threadIdx.x;
    if (tid < 16 * 3) W3s[tid] = W3[tid];
    if (tid < 16) b2s[tid] = b2[tid];
    __syncthreads();
    unsigned t = blockIdx.x * 256u + tid;
    unsigned g = t >> 1, c = t & 1u;
    if (g >= NNODES) return;
    int rs = rowstart[g], d = deg[g];
    float acc[8];
    {
        h8 s = g2sh[g * 2u + c];
#pragma unroll
        for (int k = 0; k < 8; ++k) acc[k] = (float)s.v[k];
    }
    int j = 0;
    for (; j + 4 <= d; j += 4) {
        int s0 = csr[rs + j], s1 = csr[rs + j + 1], s2 = csr[rs + j + 2], s3 = csr[rs + j + 3];
        h8 a = g2sh[(unsigned)s0 * 2u + c], bb = g2sh[(unsigned)s1 * 2u + c];
        h8 cc = g2sh[(unsigned)s2 * 2u + c], dd = g2sh[(unsigned)s3 * 2u + c];
#pragma unroll
        for (int k = 0; k < 8; ++k)
            acc[k] += ((float)a.v[k] + (float)bb.v[k]) + ((float)cc.v[k] + (float)dd.v[k]);
    }
    for (; j < d; ++j) {
        h8 a = g2sh[(unsigned)csr[rs + j] * 2u + c];
#pragma unroll
        for (int k = 0; k < 8; ++k) acc[k] += (float)a.v[k];
    }
    float di = dinv[g];
    float p0 = 0.f, p1 = 0.f, p2 = 0.f;
#pragma unroll
    for (int jj = 0; jj < 8; ++jj) {
        int ch = c * 8 + jj;
        float v = acc[jj] * di + b2s[ch];
        v = v > 0.f ? v : 0.f;
        p0 += v * W3s[ch * 3 + 0];
        p1 += v * W3s[ch * 3 + 1];
        p2 += v * W3s[ch * 3 + 2];
    }
    p0 += __shfl_xor(p0, 1);
    p1 += __shfl_xor(p1, 1);
    p2 += __shfl_xor(p2, 1);
    if (c == 0) {
        h4 o;
        o.v[0] = (h16)(p0 * di);
        o.v[1] = (h16)(p1 * di);
        o.v[2] = (h16)(p2 * di);
        o.v[3] = (h16)0.f;
        g3s4h[g] = o;
    }
}

// layer3 gather (node per lane) + bias + relu -> h3 fp32
__global__ __launch_bounds__(256) void g4h_final(const int* __restrict__ rowstart,
                                                 const int* __restrict__ deg,
                                                 const int* __restrict__ csr,
                                                 const h4* __restrict__ g3,
                                                 const float* __restrict__ dinv,
                                                 const float* __restrict__ b3,
                                                 float* __restrict__ h3) {
    unsigned g = blockIdx.x * 256u + threadIdx.x;
    if (g >= NNODES) return;
    int rs = rowstart[g], d = deg[g];
    float a0, a1, a2;
    {
        h4 s = g3[g];
        a0 = (float)s.v[0]; a1 = (float)s.v[1]; a2 = (float)s.v[2];
    }
    int j = 0;
    for (; j + 2 <= d; j += 2) {
        h4 v0 = g3[csr[rs + j]], v1 = g3[csr[rs + j + 1]];
        a0 += (float)v0.v[0] + (float)v1.v[0];
        a1 += (float)v0.v[1] + (float)v1.v[1];
        a2 += (float)v0.v[2] + (float)v1.v[2];
    }
    for (; j < d; ++j) {
        h4 v = g3[csr[rs + j]];
        a0 += (float)v.v[0]; a1 += (float)v.v[1]; a2 += (float)v.v[2];
    }
    float di = dinv[g];
    float o0 = a0 * di + b3[0];
    float o1 = a1 * di + b3[1];
    float o2 = a2 * di + b3[2];
    h3[g * 3u + 0] = o0 > 0.f ? o0 : 0.f;
    h3[g * 3u + 1] = o1 > 0.f ? o1 : 0.f;
    h3[g * 3u + 2] = o2 > 0.f ? o2 : 0.f;
}

// ================= head =================

// block = (seg, batch-group of 4); Wl1 segment staged once in LDS
__global__ __launch_bounds__(256) void k_head3(const float* __restrict__ h3,
                                               const float* __restrict__ Wl1,
                                               float* __restrict__ zpart) {
    __shared__ float Wl1s[SEGK * 32];   // 28 KB
    __shared__ float hrow[SEGK];
    __shared__ float part[8][32];
    int seg = blockIdx.x & 31, bg = blockIdx.x >> 5;
    int tid = threadIdx.x;
    int k0 = seg * SEGK;
    int cnt = HEADK - k0; if (cnt > SEGK) cnt = SEGK;
    for (int i = tid; i < cnt * 32; i += 256) Wl1s[i] = Wl1[k0 * 32 + i];
    int j = tid & 31, kg = tid >> 5;
    for (int bb = 0; bb < BPB; ++bb) {
        int b = bg * BPB + bb;
        __syncthreads();
        for (int k = tid; k < cnt; k += 256) hrow[k] = h3[b * HEADK + k0 + k];
        __syncthreads();
        float acc = 0.f;
        for (int k = kg; k < cnt; k += 8) acc += hrow[k] * Wl1s[k * 32 + j];
        part[kg][j] = acc;
        __syncthreads();
        if (tid < 32) {
            float s = 0.f;
#pragma unroll
            for (int g2 = 0; g2 < 8; ++g2) s += part[g2][tid];
            zpart[(seg * NB + b) * 32 + tid] = s;
        }
    }
}

__global__ void k_bn_final(const float* __restrict__ zpart, const float* __restrict__ bl1,
                           const float* __restrict__ gamma, const float* __restrict__ beta,
                           const float* __restrict__ Wl2, const float* __restrict__ bl2,
                           float* __restrict__ out) {
    __shared__ float zs[NB][32];
    __shared__ float scale[32], shift[32];
    int tid = threadIdx.x;  // 256
    for (int i = tid; i < NB * 32; i += 256) {
        float v = bl1[i & 31];
#pragma unroll
        for (int sgm = 0; sgm < HEAD_SEG; ++sgm) v += zpart[sgm * NB * 32 + i];
        zs[i >> 5][i & 31] = v;
    }
    __syncthreads();
    if (tid < 32) {
        float m = 0.f, v = 0.f;
        for (int b = 0; b < NB; ++b) { float xv = zs[b][tid]; m += xv; v += xv * xv; }
        m /= (float)NB;
        v = v / (float)NB - m * m;
        float sc = gamma[tid] * rsqrtf(v + BN_EPS);
        scale[tid] = sc;
        shift[tid] = beta[tid] - m * sc;
    }
    __syncthreads();
    if (tid < NB) {
        float acc = bl2[0];
#pragma unroll
        for (int j = 0; j < 32; ++j) {
            float zv = zs[tid][j] * scale[j] + shift[j];
            zv = zv > 0.f ? zv : 0.f;
            acc += zv * Wl2[j];
        }
        out[tid] = acc;
    }
}

// ================= launch =================

extern "C" void kernel_launch(void* const* d_in, const int* in_sizes, int n_in,
                              void* d_out, int out_size, void* d_ws, size_t ws_size,
                              hipStream_t stream) {
    const float* x    = (const float*)d_in[0];
    const int*   ei   = (const int*)d_in[1];
    const float* W1   = (const float*)d_in[2];
    const float* b1   = (const float*)d_in[3];
    const float* W2   = (const float*)d_in[4];
    const float* b2   = (const float*)d_in[5];
    const float* W3   = (const float*)d_in[6];
    const float* b3   = (const float*)d_in[7];
    const float* Wl1  = (const float*)d_in[8];
    const float* bl1  = (const float*)d_in[9];
    const float* gamma= (const float*)d_in[10];
    const float* beta = (const float*)d_in[11];
    const float* Wl2  = (const float*)d_in[12];
    const float* bl2  = (const float*)d_in[13];

    const int* src = ei;            // edge_index[0]
    const int* dst = ei + NEDGES;   // edge_index[1]

    char* ws = (char*)d_ws;
    size_t off = 0;
    float*    dinv     = (float*)   (ws + off); off += (size_t)NNODES * 4;
    int*      deg      = (int*)     (ws + off); off += (size_t)NNODES * 4;
    int*      counts   = (int*)     (ws + off); off += (size_t)NBUCK * NCHUNK * 4;
    int*      bases    = (int*)     (ws + off); off += (size_t)NBUCK * NCHUNK * 4;
    int*      btot     = (int*)     (ws + off); off += (size_t)NBUCK * 4;
    int*      bstart   = (int*)     (ws + off); off += (size_t)(NBUCK + 1) * 4;
    off = (off + 255) & ~(size_t)255;
    unsigned* packed   = (unsigned*)(ws + off); off += (size_t)NEDGES * 4;
    int*      rowstart = (int*)     (ws + off); off += (size_t)NNODES * 4;
    int*      csr      = (int*)     (ws + off); off += (size_t)NEDGES * 4;
    h8*       xs8h     = (h8*)      (ws + off); off += (size_t)NNODES * 16;
    h8*       g2sh     = (h8*)      (ws + off); off += (size_t)NNODES * 32;
    h4*       g3s4h    = (h4*)      (ws + off); off += (size_t)NNODES * 8;
    float*    h3       = (float*)   (ws + off); off += (size_t)NNODES * 3 * 4;
    float*    zpart    = (float*)   (ws + off); off += (size_t)HEAD_SEG * NB * 32 * 4;

    float* outp = (float*)d_out;

    // ---- CSR build (all global stores coalesced; scatter staged in LDS) + fused x*dinv fp16 pack
    k_count<<<NCHUNK, 256, 0, stream>>>(dst, counts);
    k_scanA<<<NBUCK, 256, 0, stream>>>(counts, bases, btot);
    k_scanB<<<1, NBUCK, 0, stream>>>(btot, bstart);
    k_bin_sorted<<<NCHUNK, 256, 0, stream>>>(src, dst, bases, bstart, packed);
    k_build<<<NBUCK, 256, 0, stream>>>(packed, bstart, x, deg, rowstart, dinv, csr, xs8h);

    // ---- layer1 gather + mm1 + relu + mm2 + prescale
    g8h_mm12<<<(NNODES + 255) / 256, 256, 0, stream>>>(
        rowstart, deg, csr, xs8h, dinv, W1, b1, W2, g2sh);

    // ---- layer2 gather + relu + mm3 + prescale
    g16h_mm3<<<(int)(((unsigned)NNODES * 2u + 255) / 256), 256, 0, stream>>>(
        rowstart, deg, csr, g2sh, dinv, b2, W3, g3s4h);

    // ---- layer3 gather + bias + relu
    g4h_final<<<(NNODES + 255) / 256, 256, 0, stream>>>(
        rowstart, deg, csr, g3s4h, dinv, b3, h3);

    // ---- head + BN + final linear
    k_head3<<<HEAD_SEG * BGRP, 256, 0, stream>>>(h3, Wl1, zpart);
    k_bn_final<<<1, 256, 0, stream>>>(zpart, bl1, gamma, beta, Wl2, bl2, outp);
}